// Round 1
// baseline (1591.036 us; speedup 1.0000x reference)
//
#include <hip/hip_runtime.h>

#define NN 16384
#define DIN 128
#define DH 16
#define DOUT 4
#define TJ 256

// ---------------------------------------------------------------------------
// Kernel 1: B1 = X @ W1   [N,16]   (tiny: 67 MFLOP, ~3 us)
// block = 256 threads -> 16 rows x 16 cols, one output per thread.
// ---------------------------------------------------------------------------
__global__ __launch_bounds__(256) void xw1_kernel(const float* __restrict__ X,
                                                  const float* __restrict__ W1,
                                                  float* __restrict__ B1) {
    __shared__ float sX[16 * 132];   // padded stride 132 to break bank aliasing
    __shared__ float sW[128 * 16];
    const int t = threadIdx.x;
    const int row0 = blockIdx.x * 16;

    // stage W1 (2048 floats) coalesced as float4
    const float4* W4 = (const float4*)W1;
    float4* sW4 = (float4*)sW;
    for (int i = t; i < 512; i += 256) sW4[i] = W4[i];

    // stage 16 X rows (2048 floats) coalesced, scatter into padded layout
    const float4* X4 = (const float4*)(X + (size_t)row0 * DIN);
    for (int i4 = t; i4 < 512; i4 += 256) {
        float4 v = X4[i4];
        int i = i4 * 4;
        int r = i >> 7, k = i & 127;
        float* dst = &sX[r * 132 + k];
        dst[0] = v.x; dst[1] = v.y; dst[2] = v.z; dst[3] = v.w;
    }
    __syncthreads();

    const int r = t >> 4, c = t & 15;
    float acc = 0.f;
#pragma unroll 16
    for (int k = 0; k < DIN; ++k)
        acc = fmaf(sX[r * 132 + k], sW[k * 16 + c], acc);
    B1[(size_t)(row0 + r) * DH + c] = acc;
}

// ---------------------------------------------------------------------------
// Kernel 2: G = relu(A @ B1 + b1) @ W2    [N,4]
// block = 256 thr = 4 waves; 16 rows/block (4 rows/wave); TJ=256 column tile.
// B1 tile staged TRANSPOSED in LDS, stride 257 (conflict-free both ways).
// Per lane: acc[4 rows][16 cols]; j = lane-strided (coalesced b32 A loads).
// Butterfly cross-lane reduce once at the end, then fused relu + @W2.
// ---------------------------------------------------------------------------
__global__ __launch_bounds__(256) void layer1_kernel(const float* __restrict__ A,
                                                     const float* __restrict__ B1,
                                                     const float* __restrict__ bias1,
                                                     const float* __restrict__ W2,
                                                     float* __restrict__ G) {
    __shared__ float sB[DH * 257];
    const int t = threadIdx.x;
    const int lane = t & 63;
    const int wave = t >> 6;
    const int row0 = blockIdx.x * 16 + wave * 4;
    const float* A0 = A + (size_t)row0 * NN;

    float acc[4][16];
#pragma unroll
    for (int r = 0; r < 4; ++r)
#pragma unroll
        for (int c = 0; c < 16; ++c) acc[r][c] = 0.f;

    for (int jt = 0; jt < NN; jt += TJ) {
        // A loads for this tile: 4 rows x 4 sub-chunks, issued early
        float a[4][4];
#pragma unroll
        for (int s = 0; s < 4; ++s)
#pragma unroll
            for (int r = 0; r < 4; ++r)
                a[s][r] = A0[(size_t)r * NN + jt + s * 64 + lane];

        // stage B1[jt+t][0..15] -> transposed LDS sB[c*257 + t]
        const float4* bsrc = (const float4*)(B1 + (size_t)(jt + t) * DH);
        float4 q0 = bsrc[0], q1 = bsrc[1], q2 = bsrc[2], q3 = bsrc[3];
        sB[ 0 * 257 + t] = q0.x; sB[ 1 * 257 + t] = q0.y;
        sB[ 2 * 257 + t] = q0.z; sB[ 3 * 257 + t] = q0.w;
        sB[ 4 * 257 + t] = q1.x; sB[ 5 * 257 + t] = q1.y;
        sB[ 6 * 257 + t] = q1.z; sB[ 7 * 257 + t] = q1.w;
        sB[ 8 * 257 + t] = q2.x; sB[ 9 * 257 + t] = q2.y;
        sB[10 * 257 + t] = q2.z; sB[11 * 257 + t] = q2.w;
        sB[12 * 257 + t] = q3.x; sB[13 * 257 + t] = q3.y;
        sB[14 * 257 + t] = q3.z; sB[15 * 257 + t] = q3.w;
        __syncthreads();

#pragma unroll
        for (int s = 0; s < 4; ++s) {
            const int j = s * 64 + lane;
#pragma unroll
            for (int c = 0; c < 16; ++c) {
                const float bv = sB[c * 257 + j];
#pragma unroll
                for (int r = 0; r < 4; ++r)
                    acc[r][c] = fmaf(a[s][r], bv, acc[r][c]);
            }
        }
        __syncthreads();
    }

    // cross-lane reduction: every lane ends with the full sum
#pragma unroll
    for (int r = 0; r < 4; ++r)
#pragma unroll
        for (int c = 0; c < 16; ++c) {
#pragma unroll
            for (int off = 32; off > 0; off >>= 1)
                acc[r][c] += __shfl_xor(acc[r][c], off, 64);
        }

    // epilogue: h = relu(acc + b1); g = h @ W2; lane 0 writes float4/row
#pragma unroll
    for (int r = 0; r < 4; ++r) {
        float g0 = 0.f, g1 = 0.f, g2 = 0.f, g3 = 0.f;
#pragma unroll
        for (int c = 0; c < 16; ++c) {
            float h = acc[r][c] + bias1[c];
            h = h > 0.f ? h : 0.f;
            const float4 w = *(const float4*)&W2[c * 4];
            g0 = fmaf(h, w.x, g0);
            g1 = fmaf(h, w.y, g1);
            g2 = fmaf(h, w.z, g2);
            g3 = fmaf(h, w.w, g3);
        }
        if (lane == 0)
            *(float4*)&G[(size_t)(row0 + r) * DOUT] = make_float4(g0, g1, g2, g3);
    }
}

// ---------------------------------------------------------------------------
// Kernel 3: out = A @ G + b2   [N,4]
// Same structure; G tile rows are 16 B -> aligned b128 LDS reads,
// exactly 8 phases/wave = conflict-free minimum.
// ---------------------------------------------------------------------------
__global__ __launch_bounds__(256) void layer2_kernel(const float* __restrict__ A,
                                                     const float* __restrict__ G,
                                                     const float* __restrict__ bias2,
                                                     float* __restrict__ out) {
    __shared__ float4 sG[TJ];
    const int t = threadIdx.x;
    const int lane = t & 63;
    const int wave = t >> 6;
    const int row0 = blockIdx.x * 16 + wave * 4;
    const float* A0 = A + (size_t)row0 * NN;

    float acc[4][4];
#pragma unroll
    for (int r = 0; r < 4; ++r)
#pragma unroll
        for (int d = 0; d < 4; ++d) acc[r][d] = 0.f;

    for (int jt = 0; jt < NN; jt += TJ) {
        float a[4][4];
#pragma unroll
        for (int s = 0; s < 4; ++s)
#pragma unroll
            for (int r = 0; r < 4; ++r)
                a[s][r] = A0[(size_t)r * NN + jt + s * 64 + lane];

        sG[t] = *(const float4*)&G[(size_t)(jt + t) * DOUT];
        __syncthreads();

#pragma unroll
        for (int s = 0; s < 4; ++s) {
            const float4 g = sG[s * 64 + lane];
#pragma unroll
            for (int r = 0; r < 4; ++r) {
                acc[r][0] = fmaf(a[s][r], g.x, acc[r][0]);
                acc[r][1] = fmaf(a[s][r], g.y, acc[r][1]);
                acc[r][2] = fmaf(a[s][r], g.z, acc[r][2]);
                acc[r][3] = fmaf(a[s][r], g.w, acc[r][3]);
            }
        }
        __syncthreads();
    }

#pragma unroll
    for (int r = 0; r < 4; ++r)
#pragma unroll
        for (int d = 0; d < 4; ++d) {
#pragma unroll
            for (int off = 32; off > 0; off >>= 1)
                acc[r][d] += __shfl_xor(acc[r][d], off, 64);
        }

    if (lane == 0) {
#pragma unroll
        for (int r = 0; r < 4; ++r) {
            float4 o = make_float4(acc[r][0] + bias2[0], acc[r][1] + bias2[1],
                                   acc[r][2] + bias2[2], acc[r][3] + bias2[3]);
            *(float4*)&out[(size_t)(row0 + r) * DOUT] = o;
        }
    }
}

extern "C" void kernel_launch(void* const* d_in, const int* in_sizes, int n_in,
                              void* d_out, int out_size, void* d_ws, size_t ws_size,
                              hipStream_t stream) {
    const float* A     = (const float*)d_in[0];   // [16384,16384]
    const float* X     = (const float*)d_in[1];   // [16384,128]
    const float* W1    = (const float*)d_in[2];   // [128,16]
    const float* bias1 = (const float*)d_in[3];   // [16]
    const float* W2    = (const float*)d_in[4];   // [16,4]
    const float* bias2 = (const float*)d_in[5];   // [4]
    float* out = (float*)d_out;                   // [16384,4]

    float* B1 = (float*)d_ws;                     // [16384,16] = 1 MiB
    float* G  = B1 + (size_t)NN * DH;             // [16384,4]  = 256 KiB

    xw1_kernel<<<NN / 16, 256, 0, stream>>>(X, W1, B1);
    layer1_kernel<<<NN / 16, 256, 0, stream>>>(A, B1, bias1, W2, G);
    layer2_kernel<<<NN / 16, 256, 0, stream>>>(A, G, bias2, out);
}